// Round 7
// baseline (1806.417 us; speedup 1.0000x reference)
//
#include <hip/hip_runtime.h>
#include <hip/hip_bf16.h>
#include <math.h>

typedef __hip_bfloat16 bf16;
typedef __attribute__((ext_vector_type(8))) short bf16x8;
typedef __attribute__((ext_vector_type(4))) float f32x4;

#define DEPTH  4
#define HEADS  16
#define DIM    1024
#define DHEAD  64
#define MLPD   4096
#define BB     4
#define NN     1024
#define MMK    1024
#define ROWS   (BB*NN)     // 4096 token rows
#define QKS    2048        // packed q|k row stride

__device__ inline float bitsbf(short s) {
  union { float f; unsigned u; } c; c.u = ((unsigned)(unsigned short)s) << 16; return c.f;
}
__device__ inline short bfbits(float f) {
  bf16 h = __float2bfloat16(f); return *(short*)&h;
}

// async global->LDS 16B per lane. LDS dest = wave-uniform base + lane*16B.
__device__ inline void gload_lds16(const bf16* g, bf16* l) {
  __builtin_amdgcn_global_load_lds((const __attribute__((address_space(1))) unsigned int*)g,
                                   (__attribute__((address_space(3))) unsigned int*)l, 16, 0, 0);
}

// ---------------- f32 -> bf16 convert ----------------
__global__ __launch_bounds__(256) void f2b_kernel(const float* __restrict__ in, bf16* __restrict__ out, int n) {
  int i = blockIdx.x * 256 + threadIdx.x;
  if (i < n) out[i] = __float2bfloat16(in[i]);
}

// ---------------- generalized transpose + f32->bf16 ----------------
// out[n][k] = bf16( in[(rowOff + k) * inStride + colOff + n] )
__global__ __launch_bounds__(256) void transpose_f2b(const float* __restrict__ in, bf16* __restrict__ out,
                                                     int inStride, int rowOff, int colOff, int outStride) {
  __shared__ float tile[32][33];
  int n0 = blockIdx.x * 32, k0 = blockIdx.y * 32;
  int tx = threadIdx.x, ty = threadIdx.y;          // 32 x 8
  #pragma unroll
  for (int i = 0; i < 32; i += 8)
    tile[ty + i][tx] = in[(size_t)(rowOff + k0 + ty + i) * inStride + colOff + n0 + tx];
  __syncthreads();
  #pragma unroll
  for (int i = 0; i < 32; i += 8)
    out[(size_t)(n0 + ty + i) * outStride + k0 + tx] = __float2bfloat16(tile[tx][ty + i]);
}

// ---------------- layernorm: f32 in -> bf16 out ----------------
__global__ __launch_bounds__(256) void ln_kernel(const float* __restrict__ x, const float* __restrict__ w,
                                                 const float* __restrict__ b, bf16* __restrict__ out) {
  int row = blockIdx.x, t = threadIdx.x;
  const float* xr = x + (size_t)row * DIM;
  float4 xv = *(const float4*)(xr + t * 4);
  float s  = xv.x + xv.y + xv.z + xv.w;
  float s2 = xv.x * xv.x + xv.y * xv.y + xv.z * xv.z + xv.w * xv.w;
  #pragma unroll
  for (int off = 32; off; off >>= 1) { s += __shfl_xor(s, off, 64); s2 += __shfl_xor(s2, off, 64); }
  __shared__ float sh_s[4], sh_s2[4], sh_mu, sh_rstd;
  int wid = t >> 6;
  if ((t & 63) == 0) { sh_s[wid] = s; sh_s2[wid] = s2; }
  __syncthreads();
  if (t == 0) {
    float S1 = sh_s[0] + sh_s[1] + sh_s[2] + sh_s[3];
    float S2 = sh_s2[0] + sh_s2[1] + sh_s2[2] + sh_s2[3];
    float mu = S1 * (1.0f / DIM);
    float var = S2 * (1.0f / DIM) - mu * mu;
    sh_mu = mu; sh_rstd = rsqrtf(var + 1e-5f);
  }
  __syncthreads();
  float mu = sh_mu, rstd = sh_rstd;
  float4 wv = *(const float4*)(w + t * 4);
  float4 bv = *(const float4*)(b + t * 4);
  bf16* orow = out + (size_t)row * DIM + t * 4;
  orow[0] = __float2bfloat16((xv.x - mu) * rstd * wv.x + bv.x);
  orow[1] = __float2bfloat16((xv.y - mu) * rstd * wv.y + bv.y);
  orow[2] = __float2bfloat16((xv.z - mu) * rstd * wv.z + bv.z);
  orow[3] = __float2bfloat16((xv.w - mu) * rstd * wv.w + bv.w);
}

// ---------------- GEMM BM=128 x BN=(JT*32), BK=64: C = A(M,K) x Bt(N,K)^T ----------
// Double-buffered LDS, ONE barrier per BK=64. DMA source column pre-swizzled
// (col=((l&7)^(l>>3))*8), fragment reads XOR the chunk with (row&7).
// MODE_KVT: N=2048 dispatch over [Wk|Wv]; cols<1024 -> K into qk (stride 2048,
// offset 1024); cols>=1024 -> V transposed per head into vtb[b][h][d][key].
#define MODE_PLAIN 0
#define MODE_GELU  1
#define MODE_RES   2
#define MODE_KVT   3
#define BM 128
#define BK2 64

template<int JT>
__global__ __launch_bounds__(256) void gemm_tile(const bf16* __restrict__ A, const bf16* __restrict__ Bt,
                                                 const float* __restrict__ bias, bf16* __restrict__ outb,
                                                 float* __restrict__ resf, bf16* __restrict__ vtb,
                                                 int outStride, int K, int mode) {
  constexpr int BN = JT * 32;
  __shared__ __align__(16) bf16 As[2][BM * BK2];   // 2 x 16 KB
  __shared__ __align__(16) bf16 Bs[2][BN * BK2];   // 2 x (16 or 8) KB
  int t = threadIdx.x;
  int w = t >> 6, l = t & 63;
  int l15 = l & 15, quad = l >> 4;
  int l8 = l & 7, lh = l >> 3;
  int col0 = blockIdx.x * BN, row0 = blockIdx.y * BM;
  int wm = (w >> 1) * 64, wn = (w & 1) * (JT * 16);

  f32x4 acc[4][JT] = {};

  int swk = (l8 ^ lh) * 8;
  const bf16* agB = A  + (size_t)(row0 + w * 32 + lh) * K + swk;
  const bf16* bgB = Bt + (size_t)(col0 + (JT == 4 ? w * 32 : w * 16) + lh) * K + swk;

  // prologue: tile 0 -> buf 0
  #pragma unroll
  for (int i = 0; i < 4; ++i)
    gload_lds16(agB + (size_t)(i * 8) * K, &As[0][w * 2048 + i * 512]);
  #pragma unroll
  for (int i = 0; i < (JT == 4 ? 4 : 2); ++i)
    gload_lds16(bgB + (size_t)(i * 8) * K, &Bs[0][w * (JT == 4 ? 2048 : 1024) + i * 512]);

  int cur = 0;
  for (int k0 = 0; k0 < K; k0 += BK2) {
    __syncthreads();             // drains DMA (vmcnt) + prior ds reads: buf[cur] valid
    int nxt = cur ^ 1;
    if (k0 + BK2 < K) {          // prefetch next tile under this tile's compute
      #pragma unroll
      for (int i = 0; i < 4; ++i)
        gload_lds16(agB + (size_t)(i * 8) * K + k0 + BK2, &As[nxt][w * 2048 + i * 512]);
      #pragma unroll
      for (int i = 0; i < (JT == 4 ? 4 : 2); ++i)
        gload_lds16(bgB + (size_t)(i * 8) * K + k0 + BK2, &Bs[nxt][w * (JT == 4 ? 2048 : 1024) + i * 512]);
    }
    #pragma unroll
    for (int ks2 = 0; ks2 < 2; ++ks2) {
      bf16x8 af[4], bfr[JT];
      #pragma unroll
      for (int i = 0; i < 4; ++i) {
        int R = wm + i * 16 + l15;
        af[i] = *(const bf16x8*)&As[cur][R * 64 + (((quad + 4 * ks2) ^ (l15 & 7)) * 8)];
      }
      #pragma unroll
      for (int j = 0; j < JT; ++j) {
        int R = wn + j * 16 + l15;
        bfr[j] = *(const bf16x8*)&Bs[cur][R * 64 + (((quad + 4 * ks2) ^ (l15 & 7)) * 8)];
      }
      #pragma unroll
      for (int i = 0; i < 4; ++i)
        #pragma unroll
        for (int j = 0; j < JT; ++j)
          acc[i][j] = __builtin_amdgcn_mfma_f32_16x16x32_bf16(af[i], bfr[j], acc[i][j], 0, 0, 0);
    }
    cur = nxt;
  }

  // epilogue: row = row0+wm+i*16+quad*4+r, col = col0+wn+j*16+l15
  #pragma unroll
  for (int i = 0; i < 4; ++i) {
    #pragma unroll
    for (int j = 0; j < JT; ++j) {
      int gcol = col0 + wn + j * 16 + l15;
      float bval = ((mode == MODE_GELU || mode == MODE_RES) && bias != nullptr) ? bias[gcol] : 0.0f;
      #pragma unroll
      for (int r = 0; r < 4; ++r) {
        int grow = row0 + wm + i * 16 + quad * 4 + r;
        float val = acc[i][j][r];
        if (mode == MODE_KVT) {
          if (gcol < 1024) {
            outb[(size_t)grow * QKS + 1024 + gcol] = __float2bfloat16(val);    // K
          } else {
            int vd = gcol - 1024, vh = vd >> 6, dl = vd & 63;
            int bb2 = grow >> 10, key = grow & 1023;
            vtb[((size_t)((bb2 * 16 + vh) * 64 + dl)) * 1024 + key] = __float2bfloat16(val);
          }
        } else {
          size_t idx = (size_t)grow * outStride + gcol;
          if (mode == MODE_RES) {
            resf[idx] = resf[idx] + val + bval;
          } else {
            if (mode == MODE_GELU) {
              float u = val + bval;
              val = 0.5f * u * (1.0f + erff(u * 0.70710678118654752f));
            }
            outb[idx] = __float2bfloat16(val);
          }
        }
      }
    }
  }
}

// ---------------- MFMA flash attention v3: zero-barrier, no K/V staging --------------
// K and V^T fragments are 16B-contiguous in global and L2-resident (panel 128KB/head,
// XCD-pinned via grid (bh,qt)) -> read them directly; only Pl (wave-private 16-row
// band) lives in LDS. No __syncthreads at all; 4 blocks/CU, TLP hides L2 latency.
#define ALDP 72

__global__ __launch_bounds__(256) void attn_mfma_kernel(const bf16* __restrict__ qk,
                                                        const bf16* __restrict__ vT,
                                                        bf16* __restrict__ o) {
  __shared__ __align__(16) short Pl[64][ALDP];

  int t = threadIdx.x;
  int lane = t & 63, w = t >> 6;
  int l15 = lane & 15, quad = lane >> 4;
  int bh = blockIdx.x;
  int qt = blockIdx.y;
  int b = bh >> 4, hh = bh & 15;

  bf16x8 qfrag[2];
  {
    const bf16* qp = qk + (size_t)(b * NN + qt * 64 + w * 16 + l15) * QKS + hh * DHEAD + quad * 8;
    #pragma unroll
    for (int ks = 0; ks < 2; ++ks) {
      bf16x8 raw = *(const bf16x8*)(qp + ks * 32);
      bf16x8 sc;
      #pragma unroll
      for (int e = 0; e < 8; ++e) sc[e] = bfbits(bitsbf(raw[e]) * 0.03125f);
      qfrag[ks] = sc;
    }
  }

  // K fragment base: row = key token, col = 1024 + hh*64 + (ks*4+quad)*8
  const bf16* kb = qk + (size_t)(b * MMK) * QKS + 1024 + hh * DHEAD + quad * 8;
  // V^T fragment base: row = b*1024 + hh*64 + d, col = key
  const bf16* vb0 = vT + ((size_t)(b * 1024 + hh * 64)) * 1024;

  f32x4 Oacc[4] = {{}, {}, {}, {}};
  float mrow[4] = {-1e30f, -1e30f, -1e30f, -1e30f};
  float lrow[4] = {0.f, 0.f, 0.f, 0.f};

  for (int kt = 0; kt < MMK / 64; ++kt) {
    // QK^T: B-fragment = 16B of K row (key = kt*64 + j*16 + l15)
    f32x4 S[4] = {{}, {}, {}, {}};
    bf16x8 kf[2][4];
    #pragma unroll
    for (int ks = 0; ks < 2; ++ks)
      #pragma unroll
      for (int j = 0; j < 4; ++j)
        kf[ks][j] = *(const bf16x8*)(kb + (size_t)(kt * 64 + j * 16 + l15) * QKS + ks * 32);
    #pragma unroll
    for (int ks = 0; ks < 2; ++ks)
      #pragma unroll
      for (int j = 0; j < 4; ++j)
        S[j] = __builtin_amdgcn_mfma_f32_16x16x32_bf16(qfrag[ks], kf[ks][j], S[j], 0, 0, 0);

    #pragma unroll
    for (int r = 0; r < 4; ++r) {
      float tm = fmaxf(fmaxf(S[0][r], S[1][r]), fmaxf(S[2][r], S[3][r]));
      tm = fmaxf(tm, __shfl_xor(tm, 1, 64));
      tm = fmaxf(tm, __shfl_xor(tm, 2, 64));
      tm = fmaxf(tm, __shfl_xor(tm, 4, 64));
      tm = fmaxf(tm, __shfl_xor(tm, 8, 64));
      float mn = fmaxf(mrow[r], tm);
      float alpha = __expf(mrow[r] - mn);
      mrow[r] = mn;
      float rs = 0.f;
      #pragma unroll
      for (int j = 0; j < 4; ++j) {
        float p = __expf(S[j][r] - mn);
        S[j][r] = p;
        rs += p;
      }
      rs += __shfl_xor(rs, 1, 64);
      rs += __shfl_xor(rs, 2, 64);
      rs += __shfl_xor(rs, 4, 64);
      rs += __shfl_xor(rs, 8, 64);
      lrow[r] = lrow[r] * alpha + rs;
      #pragma unroll
      for (int j = 0; j < 4; ++j) {
        Oacc[j][r] *= alpha;
        Pl[w * 16 + quad * 4 + r][j * 16 + l15] = bfbits(S[j][r]);
      }
    }

    // PV: A-fragment from wave-private Pl band (same-wave DS in-order),
    //     B-fragment = 16B of V^T row (d = j*16+l15), key = kt*64+ks*32+quad*8
    #pragma unroll
    for (int ks = 0; ks < 2; ++ks) {
      bf16x8 pa = *(const bf16x8*)&Pl[w * 16 + l15][ks * 32 + quad * 8];
      #pragma unroll
      for (int j = 0; j < 4; ++j) {
        bf16x8 vf = *(const bf16x8*)(vb0 + (size_t)(j * 16 + l15) * 1024 + kt * 64 + ks * 32 + quad * 8);
        Oacc[j] = __builtin_amdgcn_mfma_f32_16x16x32_bf16(pa, vf, Oacc[j], 0, 0, 0);
      }
    }
  }

  #pragma unroll
  for (int r = 0; r < 4; ++r) {
    float inv = 1.0f / lrow[r];
    bf16* op = o + (size_t)(b * NN + qt * 64 + w * 16 + quad * 4 + r) * DIM + hh * DHEAD;
    #pragma unroll
    for (int j = 0; j < 4; ++j)
      op[j * 16 + l15] = __float2bfloat16(Oacc[j][r] * inv);
  }
}

// ---------------- host orchestration ----------------
extern "C" void kernel_launch(void* const* d_in, const int* in_sizes, int n_in,
                              void* d_out, int out_size, void* d_ws, size_t ws_size,
                              hipStream_t stream) {
  const float* x_in = (const float*)d_in[0];
  const float* m    = (const float*)d_in[1];
  const float* Wq   = (const float*)d_in[2];
  const float* Wk   = (const float*)d_in[3];
  const float* Wv   = (const float*)d_in[4];
  const float* Wo   = (const float*)d_in[5];
  const float* bo   = (const float*)d_in[6];
  const float* ln1w = (const float*)d_in[7];
  const float* ln1b = (const float*)d_in[8];
  const float* W1   = (const float*)d_in[9];
  const float* b1   = (const float*)d_in[10];
  const float* W2   = (const float*)d_in[11];
  const float* b2   = (const float*)d_in[12];
  const float* ln2w = (const float*)d_in[13];
  const float* ln2b = (const float*)d_in[14];

  float* xf = (float*)d_out;   // fp32 residual in d_out

  char* ws = (char*)d_ws;
  // layout (44 MB): h [0,8), mb [8,16), qk [16,32) packed q|k stride 2048,
  //                 vT [32,40) per-head V^T, wt [40,44).
  //                 ffh (4096x2048) reuses qk's [16,32) in MLP phase.
  bf16* h    = (bf16*)(ws + 0);
  bf16* mb   = (bf16*)(ws + (8u  << 20));
  bf16* qk   = (bf16*)(ws + (16u << 20));
  bf16* ffh  = (bf16*)(ws + (16u << 20));
  bf16* vT   = (bf16*)(ws + (32u << 20));
  bf16* wt   = (bf16*)(ws + (40u << 20));

  const int NTOK = ROWS * DIM;

  hipMemcpyAsync(xf, x_in, (size_t)NTOK * sizeof(float), hipMemcpyDeviceToDevice, stream);
  f2b_kernel<<<dim3((NTOK + 255) / 256), dim3(256), 0, stream>>>(m, mb, NTOK);

  dim3 blk(256);
  dim3 tblk(32, 8);
  dim3 g_n1(DIM / 64, ROWS / BM);       // (16, 32) = 512 blocks, JT=2
  dim3 g_n2(2048 / 128, ROWS / BM);     // (16, 32) = 512 blocks, JT=4
  dim3 tr_1k(DIM / 32, DIM / 32);
  dim3 tr_w1(2048 / 32, DIM / 32);
  dim3 tr_w2(DIM / 32, 2048 / 32);
  dim3 attn_grid(BB * HEADS, NN / 64);  // xcd = bh & 7

  for (int L = 0; L < DEPTH; ++L) {
    const float* WqL = Wq + (size_t)L * DIM * DIM;
    const float* WkL = Wk + (size_t)L * DIM * DIM;
    const float* WvL = Wv + (size_t)L * DIM * DIM;
    const float* WoL = Wo + (size_t)L * DIM * DIM;
    const float* W1L = W1 + (size_t)L * DIM * MLPD;
    const float* W2L = W2 + (size_t)L * MLPD * DIM;

    // --- cross-attention block ---
    ln_kernel<<<dim3(ROWS), blk, 0, stream>>>(xf, ln1w + L * DIM, ln1b + L * DIM, h);

    // K|V fused: Bt = [Wk^T ; Wv^T] (2048 x 1024) in wt; K->qk, V->vT (MODE_KVT)
    transpose_f2b<<<tr_1k, tblk, 0, stream>>>(WkL, wt, DIM, 0, 0, DIM);
    transpose_f2b<<<tr_1k, tblk, 0, stream>>>(WvL, wt + 1024 * 1024, DIM, 0, 0, DIM);
    gemm_tile<4><<<g_n2, blk, 0, stream>>>(mb, wt, nullptr, qk, nullptr, vT, QKS, DIM, MODE_KVT);

    transpose_f2b<<<tr_1k, tblk, 0, stream>>>(WqL, wt, DIM, 0, 0, DIM);
    gemm_tile<2><<<g_n1, blk, 0, stream>>>(h, wt, nullptr, qk, nullptr, nullptr, QKS, DIM, MODE_PLAIN);

    attn_mfma_kernel<<<attn_grid, blk, 0, stream>>>(qk, vT, h);

    transpose_f2b<<<tr_1k, tblk, 0, stream>>>(WoL, wt, DIM, 0, 0, DIM);
    gemm_tile<2><<<g_n1, blk, 0, stream>>>(h, wt, bo + L * DIM, nullptr, xf, nullptr, DIM, DIM, MODE_RES);

    // --- MLP block (two N=2048 halves; ffh reuses qk space) ---
    ln_kernel<<<dim3(ROWS), blk, 0, stream>>>(xf, ln2w + L * DIM, ln2b + L * DIM, h);

    for (int half = 0; half < 2; ++half) {
      transpose_f2b<<<tr_w1, tblk, 0, stream>>>(W1L, wt, MLPD, 0, half * 2048, DIM);
      gemm_tile<4><<<g_n2, blk, 0, stream>>>(h, wt, b1 + (size_t)L * MLPD + half * 2048, ffh, nullptr,
                                             nullptr, 2048, DIM, MODE_GELU);
      transpose_f2b<<<tr_w2, tblk, 0, stream>>>(W2L, wt, DIM, half * 2048, 0, 2048);
      gemm_tile<2><<<g_n1, blk, 0, stream>>>(ffh, wt, (half == 0) ? (b2 + (size_t)L * DIM) : nullptr,
                                             nullptr, xf, nullptr, DIM, 2048, MODE_RES);
    }
  }
}

// Round 8
// 1605.140 us; speedup vs baseline: 1.1254x; 1.1254x over previous
//
#include <hip/hip_runtime.h>
#include <hip/hip_bf16.h>
#include <math.h>

typedef __hip_bfloat16 bf16;
typedef __attribute__((ext_vector_type(8))) short bf16x8;
typedef __attribute__((ext_vector_type(4))) float f32x4;

#define DEPTH  4
#define HEADS  16
#define DIM    1024
#define DHEAD  64
#define MLPD   4096
#define BB     4
#define NN     1024
#define MMK    1024
#define ROWS   (BB*NN)     // 4096 token rows
#define QKVS   3072        // packed qkv row stride

__device__ inline float bitsbf(short s) {
  union { float f; unsigned u; } c; c.u = ((unsigned)(unsigned short)s) << 16; return c.f;
}
__device__ inline short bfbits(float f) {
  bf16 h = __float2bfloat16(f); return *(short*)&h;
}

// async global->LDS 16B per lane. LDS dest = wave-uniform base + lane*16B.
__device__ inline void gload_lds16(const bf16* g, bf16* l) {
  __builtin_amdgcn_global_load_lds((const __attribute__((address_space(1))) unsigned int*)g,
                                   (__attribute__((address_space(3))) unsigned int*)l, 16, 0, 0);
}

// ---------------- f32 -> bf16 convert ----------------
__global__ __launch_bounds__(256) void f2b_kernel(const float* __restrict__ in, bf16* __restrict__ out, int n) {
  int i = blockIdx.x * 256 + threadIdx.x;
  if (i < n) out[i] = __float2bfloat16(in[i]);
}

// ---------------- generalized transpose + f32->bf16 ----------------
// out[n][k] = bf16( in[(rowOff + k) * inStride + colOff + n] )
__global__ __launch_bounds__(256) void transpose_f2b(const float* __restrict__ in, bf16* __restrict__ out,
                                                     int inStride, int rowOff, int colOff, int outStride) {
  __shared__ float tile[32][33];
  int n0 = blockIdx.x * 32, k0 = blockIdx.y * 32;
  int tx = threadIdx.x, ty = threadIdx.y;          // 32 x 8
  #pragma unroll
  for (int i = 0; i < 32; i += 8)
    tile[ty + i][tx] = in[(size_t)(rowOff + k0 + ty + i) * inStride + colOff + n0 + tx];
  __syncthreads();
  #pragma unroll
  for (int i = 0; i < 32; i += 8)
    out[(size_t)(n0 + ty + i) * outStride + k0 + tx] = __float2bfloat16(tile[tx][ty + i]);
}

// ---------------- layernorm: f32 in -> bf16 out ----------------
__global__ __launch_bounds__(256) void ln_kernel(const float* __restrict__ x, const float* __restrict__ w,
                                                 const float* __restrict__ b, bf16* __restrict__ out) {
  int row = blockIdx.x, t = threadIdx.x;
  const float* xr = x + (size_t)row * DIM;
  float4 xv = *(const float4*)(xr + t * 4);
  float s  = xv.x + xv.y + xv.z + xv.w;
  float s2 = xv.x * xv.x + xv.y * xv.y + xv.z * xv.z + xv.w * xv.w;
  #pragma unroll
  for (int off = 32; off; off >>= 1) { s += __shfl_xor(s, off, 64); s2 += __shfl_xor(s2, off, 64); }
  __shared__ float sh_s[4], sh_s2[4], sh_mu, sh_rstd;
  int wid = t >> 6;
  if ((t & 63) == 0) { sh_s[wid] = s; sh_s2[wid] = s2; }
  __syncthreads();
  if (t == 0) {
    float S1 = sh_s[0] + sh_s[1] + sh_s[2] + sh_s[3];
    float S2 = sh_s2[0] + sh_s2[1] + sh_s2[2] + sh_s2[3];
    float mu = S1 * (1.0f / DIM);
    float var = S2 * (1.0f / DIM) - mu * mu;
    sh_mu = mu; sh_rstd = rsqrtf(var + 1e-5f);
  }
  __syncthreads();
  float mu = sh_mu, rstd = sh_rstd;
  float4 wv = *(const float4*)(w + t * 4);
  float4 bv = *(const float4*)(b + t * 4);
  bf16* orow = out + (size_t)row * DIM + t * 4;
  orow[0] = __float2bfloat16((xv.x - mu) * rstd * wv.x + bv.x);
  orow[1] = __float2bfloat16((xv.y - mu) * rstd * wv.y + bv.y);
  orow[2] = __float2bfloat16((xv.z - mu) * rstd * wv.z + bv.z);
  orow[3] = __float2bfloat16((xv.w - mu) * rstd * wv.w + bv.w);
}

// ---------------- GEMM BM=64 x BN=(JT*32), BK=64: C = A(M,K) x Bt(N,K)^T ----------
// Latency-bound regime (r7 analysis: 4.6x above LDS-BW floor) -> maximize blocks/CU.
// BM=64: 1024-block grids = 4 blk/CU (JT=2, 32KB) / 3 blk/CU (JT=4, 48KB); cross-
// block TLP hides each block's DMA drain. gridDim.x=16 -> flat%8 = x%8: same-B-panel
// blocks auto-pin to one XCD. DMA source col pre-swizzled ((l&7)^(l>>3))*8, fragment
// reads XOR chunk with (row&7). Wave grid 2x2: per-wave 32 x JT*16, acc[2][JT].
#define MODE_PLAIN 0
#define MODE_GELU  1
#define MODE_RES   2
#define BMh 64
#define BK2 64

template<int JT>
__global__ __launch_bounds__(256) void gemm_tile(const bf16* __restrict__ A, const bf16* __restrict__ Bt,
                                                 const float* __restrict__ bias, bf16* __restrict__ outb,
                                                 float* __restrict__ resf, int outStride, int K, int mode) {
  constexpr int BN = JT * 32;
  constexpr int BISS = JT;                         // B DMA issues per wave (2 or 4)
  __shared__ __align__(16) bf16 As[2][BMh * BK2];  // 2 x 8 KB
  __shared__ __align__(16) bf16 Bs[2][BN * BK2];   // 2 x (8 or 16) KB
  int t = threadIdx.x;
  int w = t >> 6, l = t & 63;
  int l15 = l & 15, quad = l >> 4;
  int l8 = l & 7, lh = l >> 3;
  int col0 = blockIdx.x * BN, row0 = blockIdx.y * BMh;
  int wm = (w >> 1) * 32, wn = (w & 1) * (JT * 16);

  f32x4 acc[2][JT] = {};

  int swk = (l8 ^ lh) * 8;
  // A: 2 issues/wave, rows w*16 + i*8 + lh (covers 0..63); (row&7)==lh
  const bf16* agB = A + (size_t)(row0 + w * 16 + lh) * K + swk;
  // B: JT issues/wave, rows w*(JT*8) + i*8 + lh (covers 0..BN-1)
  const bf16* bgB = Bt + (size_t)(col0 + w * (JT * 8) + lh) * K + swk;

  // prologue: tile 0 -> buf 0
  #pragma unroll
  for (int i = 0; i < 2; ++i)
    gload_lds16(agB + (size_t)(i * 8) * K, &As[0][w * 1024 + i * 512]);
  #pragma unroll
  for (int i = 0; i < BISS; ++i)
    gload_lds16(bgB + (size_t)(i * 8) * K, &Bs[0][w * (BISS * 512) + i * 512]);

  int cur = 0;
  for (int k0 = 0; k0 < K; k0 += BK2) {
    __syncthreads();             // drains DMA (vmcnt): buf[cur] valid
    int nxt = cur ^ 1;
    if (k0 + BK2 < K) {          // prefetch next tile under this tile's compute
      #pragma unroll
      for (int i = 0; i < 2; ++i)
        gload_lds16(agB + (size_t)(i * 8) * K + k0 + BK2, &As[nxt][w * 1024 + i * 512]);
      #pragma unroll
      for (int i = 0; i < BISS; ++i)
        gload_lds16(bgB + (size_t)(i * 8) * K + k0 + BK2, &Bs[nxt][w * (BISS * 512) + i * 512]);
    }
    #pragma unroll
    for (int ks2 = 0; ks2 < 2; ++ks2) {
      bf16x8 af[2], bfr[JT];
      #pragma unroll
      for (int i = 0; i < 2; ++i) {
        int R = wm + i * 16 + l15;
        af[i] = *(const bf16x8*)&As[cur][R * 64 + (((quad + 4 * ks2) ^ (l15 & 7)) * 8)];
      }
      #pragma unroll
      for (int j = 0; j < JT; ++j) {
        int R = wn + j * 16 + l15;
        bfr[j] = *(const bf16x8*)&Bs[cur][R * 64 + (((quad + 4 * ks2) ^ (l15 & 7)) * 8)];
      }
      #pragma unroll
      for (int i = 0; i < 2; ++i)
        #pragma unroll
        for (int j = 0; j < JT; ++j)
          acc[i][j] = __builtin_amdgcn_mfma_f32_16x16x32_bf16(af[i], bfr[j], acc[i][j], 0, 0, 0);
    }
    cur = nxt;
  }

  // epilogue: row = row0+wm+i*16+quad*4+r, col = col0+wn+j*16+l15
  #pragma unroll
  for (int i = 0; i < 2; ++i) {
    #pragma unroll
    for (int j = 0; j < JT; ++j) {
      int gcol = col0 + wn + j * 16 + l15;
      float bval = (mode != MODE_PLAIN && bias != nullptr) ? bias[gcol] : 0.0f;
      #pragma unroll
      for (int r = 0; r < 4; ++r) {
        int grow = row0 + wm + i * 16 + quad * 4 + r;
        float val = acc[i][j][r];
        size_t idx = (size_t)grow * outStride + gcol;
        if (mode == MODE_RES) {
          resf[idx] = resf[idx] + val + bval;
        } else {
          if (mode == MODE_GELU) {
            float u = val + bval;
            val = 0.5f * u * (1.0f + erff(u * 0.70710678118654752f));
          }
          outb[idx] = __float2bfloat16(val);
        }
      }
    }
  }
}

// ---------------- MFMA flash attention (packed qkv, row stride QKVS) ----------------
// v2 (round-6 measured, 80.9us): double-buffered K (DMA, XOR-swizzled source) and V
// (issue-early loads, scalar-transpose store after PV). One barrier per tile.
// Grid (bh, qt): K/V panel pinned to one XCD's L2 (FETCH 69.7 -> 12.3 MB, r4).
#define ALDP 72

__global__ __launch_bounds__(256) void attn_mfma_kernel(const bf16* __restrict__ qkv, bf16* __restrict__ o) {
  __shared__ __align__(16) bf16  Kl[2][64 * 64];   // swizzled linear [row][chunk^row&7]
  __shared__ __align__(16) short Vt[2][64][ALDP];  // V^T [d][key], padded
  __shared__ __align__(16) short Pl[64][ALDP];

  int t = threadIdx.x;
  int lane = t & 63, w = t >> 6;
  int l15 = lane & 15, quad = lane >> 4;
  int bh = blockIdx.x;             // swapped grid
  int qt = blockIdx.y;
  int b = bh >> 4, hh = bh & 15;

  const bf16* q = qkv;
  const bf16* k = qkv + 1024;
  const bf16* v = qkv + 2048;

  // K staging via DMA: wave w stages its 16-row band, chunk pre-swizzled so the
  // linear LDS write produces layout [row][ (c ^ (row&7))*8 ].
  int krow = w * 16 + (lane >> 3);                    // issue 0 rows; issue 1 = +8
  int kcol = ((lane & 7) ^ (lane >> 3)) * 8;          // (row&7) == lane>>3 for both issues
  const bf16* kg0 = k + (size_t)(b * MMK + krow) * QKVS + hh * DHEAD + kcol;
  const bf16* kg1 = kg0 + (size_t)8 * QKVS;

  // V staging source (reg -> scalar transpose, unchanged addressing)
  int srow = t >> 2, sc0 = (t & 3) * 16;
  const bf16* vg = v + (size_t)(b * MMK + srow) * QKVS + hh * DHEAD + sc0;

  bf16x8 qfrag[2];
  {
    const bf16* qp = q + (size_t)(b * NN + qt * 64 + w * 16 + l15) * QKVS + hh * DHEAD + quad * 8;
    #pragma unroll
    for (int ks = 0; ks < 2; ++ks) {
      bf16x8 raw = *(const bf16x8*)(qp + ks * 32);
      bf16x8 sc;
      #pragma unroll
      for (int e = 0; e < 8; ++e) sc[e] = bfbits(bitsbf(raw[e]) * 0.03125f);
      qfrag[ks] = sc;
    }
  }

  // prologue: tile 0 -> buffer 0
  gload_lds16(kg0, &Kl[0][w * 1024]);
  gload_lds16(kg1, &Kl[0][w * 1024 + 512]);
  {
    bf16x8 v0 = *(const bf16x8*)vg;
    bf16x8 v1 = *(const bf16x8*)(vg + 8);
    #pragma unroll
    for (int e = 0; e < 8; ++e) {
      Vt[0][sc0 + e][srow]     = v0[e];
      Vt[0][sc0 + 8 + e][srow] = v1[e];
    }
  }

  f32x4 Oacc[4] = {{}, {}, {}, {}};
  float mrow[4] = {-1e30f, -1e30f, -1e30f, -1e30f};
  float lrow[4] = {0.f, 0.f, 0.f, 0.f};

  int cur = 0;
  for (int kt = 0; kt < MMK / 64; ++kt) {
    __syncthreads();             // buf[cur] valid (drains DMA vmcnt + prev V stores)
    int nxt = cur ^ 1;
    bool more = (kt + 1 < MMK / 64);
    bf16x8 nv0, nv1;
    if (more) {
      const bf16* vgn = vg + (size_t)(kt + 1) * 64 * QKVS;
      nv0 = *(const bf16x8*)vgn;          // issue V loads first (vmcnt wait for their
      nv1 = *(const bf16x8*)(vgn + 8);    //  use won't drain K DMAs issued after)
      gload_lds16(kg0 + (size_t)(kt + 1) * 64 * QKVS, &Kl[nxt][w * 1024]);
      gload_lds16(kg1 + (size_t)(kt + 1) * 64 * QKVS, &Kl[nxt][w * 1024 + 512]);
    }

    // QK^T from swizzled K: row = j*16+l15, chunk = (ks*4+quad) ^ (l15&7)
    f32x4 S[4] = {{}, {}, {}, {}};
    #pragma unroll
    for (int ks = 0; ks < 2; ++ks) {
      #pragma unroll
      for (int j = 0; j < 4; ++j) {
        bf16x8 bfr = *(const bf16x8*)&Kl[cur][(j * 16 + l15) * 64 + (((ks * 4 + quad) ^ (l15 & 7)) * 8)];
        S[j] = __builtin_amdgcn_mfma_f32_16x16x32_bf16(qfrag[ks], bfr, S[j], 0, 0, 0);
      }
    }

    #pragma unroll
    for (int r = 0; r < 4; ++r) {
      float tm = fmaxf(fmaxf(S[0][r], S[1][r]), fmaxf(S[2][r], S[3][r]));
      tm = fmaxf(tm, __shfl_xor(tm, 1, 64));
      tm = fmaxf(tm, __shfl_xor(tm, 2, 64));
      tm = fmaxf(tm, __shfl_xor(tm, 4, 64));
      tm = fmaxf(tm, __shfl_xor(tm, 8, 64));
      float mn = fmaxf(mrow[r], tm);
      float alpha = __expf(mrow[r] - mn);
      mrow[r] = mn;
      float rs = 0.f;
      #pragma unroll
      for (int j = 0; j < 4; ++j) {
        float p = __expf(S[j][r] - mn);
        S[j][r] = p;
        rs += p;
      }
      rs += __shfl_xor(rs, 1, 64);
      rs += __shfl_xor(rs, 2, 64);
      rs += __shfl_xor(rs, 4, 64);
      rs += __shfl_xor(rs, 8, 64);
      lrow[r] = lrow[r] * alpha + rs;
      #pragma unroll
      for (int j = 0; j < 4; ++j) {
        Oacc[j][r] *= alpha;
        Pl[w * 16 + quad * 4 + r][j * 16 + l15] = bfbits(S[j][r]);
      }
    }

    // PV from Vt[cur] and Pl (Pl band is wave-private; DS in-order per wave)
    #pragma unroll
    for (int ks = 0; ks < 2; ++ks) {
      bf16x8 pa = *(const bf16x8*)&Pl[w * 16 + l15][ks * 32 + quad * 8];
      #pragma unroll
      for (int j = 0; j < 4; ++j) {
        bf16x8 vb = *(const bf16x8*)&Vt[cur][j * 16 + l15][ks * 32 + quad * 8];
        Oacc[j] = __builtin_amdgcn_mfma_f32_16x16x32_bf16(pa, vb, Oacc[j], 0, 0, 0);
      }
    }

    // write-late: stage next V tile into Vt[nxt]
    if (more) {
      #pragma unroll
      for (int e = 0; e < 8; ++e) {
        Vt[nxt][sc0 + e][srow]     = nv0[e];
        Vt[nxt][sc0 + 8 + e][srow] = nv1[e];
      }
    }
    cur = nxt;
  }

  #pragma unroll
  for (int r = 0; r < 4; ++r) {
    float inv = 1.0f / lrow[r];
    bf16* op = o + (size_t)(b * NN + qt * 64 + w * 16 + quad * 4 + r) * DIM + hh * DHEAD;
    #pragma unroll
    for (int j = 0; j < 4; ++j)
      op[j * 16 + l15] = __float2bfloat16(Oacc[j][r] * inv);
  }
}

// ---------------- host orchestration ----------------
extern "C" void kernel_launch(void* const* d_in, const int* in_sizes, int n_in,
                              void* d_out, int out_size, void* d_ws, size_t ws_size,
                              hipStream_t stream) {
  const float* x_in = (const float*)d_in[0];
  const float* m    = (const float*)d_in[1];
  const float* Wq   = (const float*)d_in[2];
  const float* Wk   = (const float*)d_in[3];
  const float* Wv   = (const float*)d_in[4];
  const float* Wo   = (const float*)d_in[5];
  const float* bo   = (const float*)d_in[6];
  const float* ln1w = (const float*)d_in[7];
  const float* ln1b = (const float*)d_in[8];
  const float* W1   = (const float*)d_in[9];
  const float* b1   = (const float*)d_in[10];
  const float* W2   = (const float*)d_in[11];
  const float* b2   = (const float*)d_in[12];
  const float* ln2w = (const float*)d_in[13];
  const float* ln2b = (const float*)d_in[14];

  float* xf = (float*)d_out;   // fp32 residual in d_out

  char* ws = (char*)d_ws;
  // layout (44 MB): h [0,8), mb [8,16), qkv [16,40) packed (4096 x 3072 bf16),
  //                 wt [40,44). ffh (4096x2048) reuses [16,32) in MLP phase.
  bf16* h    = (bf16*)(ws + 0);
  bf16* mb   = (bf16*)(ws + (8u  << 20));
  bf16* qkv  = (bf16*)(ws + (16u << 20));
  bf16* ffh  = (bf16*)(ws + (16u << 20));
  bf16* wt   = (bf16*)(ws + (40u << 20));

  const int NTOK = ROWS * DIM;

  hipMemcpyAsync(xf, x_in, (size_t)NTOK * sizeof(float), hipMemcpyDeviceToDevice, stream);
  f2b_kernel<<<dim3((NTOK + 255) / 256), dim3(256), 0, stream>>>(m, mb, NTOK);

  dim3 blk(256);
  dim3 tblk(32, 8);
  dim3 g_n1(DIM / 64, ROWS / BMh);      // (16, 64) = 1024 blocks, JT=2, 4 blk/CU
  dim3 g_n2(2048 / 128, ROWS / BMh);    // (16, 64) = 1024 blocks, JT=4, 3 blk/CU
  dim3 tr_1k(DIM / 32, DIM / 32);
  dim3 tr_w1(2048 / 32, DIM / 32);
  dim3 tr_w2(DIM / 32, 2048 / 32);
  dim3 attn_grid(BB * HEADS, NN / 64);  // xcd = bh & 7

  for (int L = 0; L < DEPTH; ++L) {
    const float* WqL = Wq + (size_t)L * DIM * DIM;
    const float* WkL = Wk + (size_t)L * DIM * DIM;
    const float* WvL = Wv + (size_t)L * DIM * DIM;
    const float* WoL = Wo + (size_t)L * DIM * DIM;
    const float* W1L = W1 + (size_t)L * DIM * MLPD;
    const float* W2L = W2 + (size_t)L * MLPD * DIM;

    // --- cross-attention block ---
    ln_kernel<<<dim3(ROWS), blk, 0, stream>>>(xf, ln1w + L * DIM, ln1b + L * DIM, h);

    // K|V fused: Bt = [Wk^T ; Wv^T] (2048 x 1024) in wt
    transpose_f2b<<<tr_1k, tblk, 0, stream>>>(WkL, wt, DIM, 0, 0, DIM);
    transpose_f2b<<<tr_1k, tblk, 0, stream>>>(WvL, wt + 1024 * 1024, DIM, 0, 0, DIM);
    gemm_tile<4><<<g_n2, blk, 0, stream>>>(mb, wt, nullptr, qkv + 1024, nullptr, QKVS, DIM, MODE_PLAIN);

    transpose_f2b<<<tr_1k, tblk, 0, stream>>>(WqL, wt, DIM, 0, 0, DIM);
    gemm_tile<2><<<g_n1, blk, 0, stream>>>(h, wt, nullptr, qkv, nullptr, QKVS, DIM, MODE_PLAIN);

    attn_mfma_kernel<<<attn_grid, blk, 0, stream>>>(qkv, h);

    transpose_f2b<<<tr_1k, tblk, 0, stream>>>(WoL, wt, DIM, 0, 0, DIM);
    gemm_tile<2><<<g_n1, blk, 0, stream>>>(h, wt, bo + L * DIM, nullptr, xf, DIM, DIM, MODE_RES);

    // --- MLP block (two N=2048 halves; ffh reuses qkv space) ---
    ln_kernel<<<dim3(ROWS), blk, 0, stream>>>(xf, ln2w + L * DIM, ln2b + L * DIM, h);

    for (int half = 0; half < 2; ++half) {
      transpose_f2b<<<tr_w1, tblk, 0, stream>>>(W1L, wt, MLPD, 0, half * 2048, DIM);
      gemm_tile<4><<<g_n2, blk, 0, stream>>>(h, wt, b1 + (size_t)L * MLPD + half * 2048, ffh, nullptr,
                                             2048, DIM, MODE_GELU);
      transpose_f2b<<<tr_w2, tblk, 0, stream>>>(W2L, wt, DIM, half * 2048, 0, 2048);
      gemm_tile<2><<<g_n1, blk, 0, stream>>>(ffh, wt, (half == 0) ? (b2 + (size_t)L * DIM) : nullptr,
                                             nullptr, xf, DIM, 2048, MODE_RES);
    }
  }
}

// Round 9
// 1515.224 us; speedup vs baseline: 1.1922x; 1.0593x over previous
//
#include <hip/hip_runtime.h>
#include <hip/hip_bf16.h>
#include <math.h>

typedef __hip_bfloat16 bf16;
typedef __attribute__((ext_vector_type(8))) short bf16x8;
typedef __attribute__((ext_vector_type(4))) float f32x4;

#define DEPTH  4
#define HEADS  16
#define DIM    1024
#define DHEAD  64
#define MLPD   4096
#define BB     4
#define NN     1024
#define MMK    1024
#define ROWS   (BB*NN)     // 4096 token rows
#define QKVS   3072        // packed qkv row stride

__device__ inline float bitsbf(short s) {
  union { float f; unsigned u; } c; c.u = ((unsigned)(unsigned short)s) << 16; return c.f;
}
__device__ inline short bfbits(float f) {
  bf16 h = __float2bfloat16(f); return *(short*)&h;
}

// async global->LDS 16B per lane. LDS dest = wave-uniform base + lane*16B.
__device__ inline void gload_lds16(const bf16* g, bf16* l) {
  __builtin_amdgcn_global_load_lds((const __attribute__((address_space(1))) unsigned int*)g,
                                   (__attribute__((address_space(3))) unsigned int*)l, 16, 0, 0);
}

// ---------------- f32 -> bf16 convert ----------------
__global__ __launch_bounds__(256) void f2b_kernel(const float* __restrict__ in, bf16* __restrict__ out, int n) {
  int i = blockIdx.x * 256 + threadIdx.x;
  if (i < n) out[i] = __float2bfloat16(in[i]);
}

// ---------------- generalized transpose + f32->bf16 ----------------
// out[n][k] = bf16( in[(rowOff + k) * inStride + colOff + n] )
__global__ __launch_bounds__(256) void transpose_f2b(const float* __restrict__ in, bf16* __restrict__ out,
                                                     int inStride, int rowOff, int colOff, int outStride) {
  __shared__ float tile[32][33];
  int n0 = blockIdx.x * 32, k0 = blockIdx.y * 32;
  int tx = threadIdx.x, ty = threadIdx.y;          // 32 x 8
  #pragma unroll
  for (int i = 0; i < 32; i += 8)
    tile[ty + i][tx] = in[(size_t)(rowOff + k0 + ty + i) * inStride + colOff + n0 + tx];
  __syncthreads();
  #pragma unroll
  for (int i = 0; i < 32; i += 8)
    out[(size_t)(n0 + ty + i) * outStride + k0 + tx] = __float2bfloat16(tile[tx][ty + i]);
}

// ---------------- layernorm: f32 in -> bf16 out ----------------
__global__ __launch_bounds__(256) void ln_kernel(const float* __restrict__ x, const float* __restrict__ w,
                                                 const float* __restrict__ b, bf16* __restrict__ out) {
  int row = blockIdx.x, t = threadIdx.x;
  const float* xr = x + (size_t)row * DIM;
  float4 xv = *(const float4*)(xr + t * 4);
  float s  = xv.x + xv.y + xv.z + xv.w;
  float s2 = xv.x * xv.x + xv.y * xv.y + xv.z * xv.z + xv.w * xv.w;
  #pragma unroll
  for (int off = 32; off; off >>= 1) { s += __shfl_xor(s, off, 64); s2 += __shfl_xor(s2, off, 64); }
  __shared__ float sh_s[4], sh_s2[4], sh_mu, sh_rstd;
  int wid = t >> 6;
  if ((t & 63) == 0) { sh_s[wid] = s; sh_s2[wid] = s2; }
  __syncthreads();
  if (t == 0) {
    float S1 = sh_s[0] + sh_s[1] + sh_s[2] + sh_s[3];
    float S2 = sh_s2[0] + sh_s2[1] + sh_s2[2] + sh_s2[3];
    float mu = S1 * (1.0f / DIM);
    float var = S2 * (1.0f / DIM) - mu * mu;
    sh_mu = mu; sh_rstd = rsqrtf(var + 1e-5f);
  }
  __syncthreads();
  float mu = sh_mu, rstd = sh_rstd;
  float4 wv = *(const float4*)(w + t * 4);
  float4 bv = *(const float4*)(b + t * 4);
  bf16* orow = out + (size_t)row * DIM + t * 4;
  orow[0] = __float2bfloat16((xv.x - mu) * rstd * wv.x + bv.x);
  orow[1] = __float2bfloat16((xv.y - mu) * rstd * wv.y + bv.y);
  orow[2] = __float2bfloat16((xv.z - mu) * rstd * wv.z + bv.z);
  orow[3] = __float2bfloat16((xv.w - mu) * rstd * wv.w + bv.w);
}

// ---------------- GEMM BM=128 x BN=(JT*32), BK=64 (round-6 proven config) ----------
// Double-buffered LDS, ONE barrier per BK=64. DMA source column pre-swizzled
// (col=((l&7)^(l>>3))*8), fragment reads XOR the chunk with (row&7).
#define MODE_PLAIN 0
#define MODE_GELU  1
#define MODE_RES   2
#define BM 128
#define BK2 64

template<int JT>
__global__ __launch_bounds__(256) void gemm_tile(const bf16* __restrict__ A, const bf16* __restrict__ Bt,
                                                 const float* __restrict__ bias, bf16* __restrict__ outb,
                                                 float* __restrict__ resf, int outStride, int K, int mode) {
  constexpr int BN = JT * 32;
  __shared__ __align__(16) bf16 As[2][BM * BK2];   // 2 x 16 KB
  __shared__ __align__(16) bf16 Bs[2][BN * BK2];   // 2 x (16 or 8) KB
  int t = threadIdx.x;
  int w = t >> 6, l = t & 63;
  int l15 = l & 15, quad = l >> 4;
  int l8 = l & 7, lh = l >> 3;
  int col0 = blockIdx.x * BN, row0 = blockIdx.y * BM;
  int wm = (w >> 1) * 64, wn = (w & 1) * (JT * 16);

  f32x4 acc[4][JT] = {};

  int swk = (l8 ^ lh) * 8;
  const bf16* agB = A  + (size_t)(row0 + w * 32 + lh) * K + swk;
  const bf16* bgB = Bt + (size_t)(col0 + (JT == 4 ? w * 32 : w * 16) + lh) * K + swk;

  // prologue: tile 0 -> buf 0
  #pragma unroll
  for (int i = 0; i < 4; ++i)
    gload_lds16(agB + (size_t)(i * 8) * K, &As[0][w * 2048 + i * 512]);
  #pragma unroll
  for (int i = 0; i < (JT == 4 ? 4 : 2); ++i)
    gload_lds16(bgB + (size_t)(i * 8) * K, &Bs[0][w * (JT == 4 ? 2048 : 1024) + i * 512]);

  int cur = 0;
  for (int k0 = 0; k0 < K; k0 += BK2) {
    __syncthreads();             // drains DMA (vmcnt) + prior ds reads: buf[cur] valid
    int nxt = cur ^ 1;
    if (k0 + BK2 < K) {          // prefetch next tile under this tile's compute
      #pragma unroll
      for (int i = 0; i < 4; ++i)
        gload_lds16(agB + (size_t)(i * 8) * K + k0 + BK2, &As[nxt][w * 2048 + i * 512]);
      #pragma unroll
      for (int i = 0; i < (JT == 4 ? 4 : 2); ++i)
        gload_lds16(bgB + (size_t)(i * 8) * K + k0 + BK2, &Bs[nxt][w * (JT == 4 ? 2048 : 1024) + i * 512]);
    }
    #pragma unroll
    for (int ks2 = 0; ks2 < 2; ++ks2) {
      bf16x8 af[4], bfr[JT];
      #pragma unroll
      for (int i = 0; i < 4; ++i) {
        int R = wm + i * 16 + l15;
        af[i] = *(const bf16x8*)&As[cur][R * 64 + (((quad + 4 * ks2) ^ (l15 & 7)) * 8)];
      }
      #pragma unroll
      for (int j = 0; j < JT; ++j) {
        int R = wn + j * 16 + l15;
        bfr[j] = *(const bf16x8*)&Bs[cur][R * 64 + (((quad + 4 * ks2) ^ (l15 & 7)) * 8)];
      }
      #pragma unroll
      for (int i = 0; i < 4; ++i)
        #pragma unroll
        for (int j = 0; j < JT; ++j)
          acc[i][j] = __builtin_amdgcn_mfma_f32_16x16x32_bf16(af[i], bfr[j], acc[i][j], 0, 0, 0);
    }
    cur = nxt;
  }

  // epilogue: row = row0+wm+i*16+quad*4+r, col = col0+wn+j*16+l15
  #pragma unroll
  for (int i = 0; i < 4; ++i) {
    #pragma unroll
    for (int j = 0; j < JT; ++j) {
      int gcol = col0 + wn + j * 16 + l15;
      float bval = (mode != MODE_PLAIN && bias != nullptr) ? bias[gcol] : 0.0f;
      #pragma unroll
      for (int r = 0; r < 4; ++r) {
        int grow = row0 + wm + i * 16 + quad * 4 + r;
        float val = acc[i][j][r];
        size_t idx = (size_t)grow * outStride + gcol;
        if (mode == MODE_RES) {
          resf[idx] = resf[idx] + val + bval;
        } else {
          if (mode == MODE_GELU) {
            float u = val + bval;
            val = 0.5f * u * (1.0f + erff(u * 0.70710678118654752f));
          }
          outb[idx] = __float2bfloat16(val);
        }
      }
    }
  }
}

// ---------------- MFMA flash attention v2-wide: QBLK=128, 8 waves --------------------
// Same verified inner algorithm as round-6 v2 (swizzled K DMA, issue-early/write-late
// V, one barrier/tile), but each block processes 128 q-rows: staging volume, barrier
// drains, and V-transpose conflicts amortize 2x per FLOP; 16 waves/CU.
#define ALDP 72

__global__ __launch_bounds__(512) void attn_mfma_kernel(const bf16* __restrict__ qkv, bf16* __restrict__ o) {
  __shared__ __align__(16) bf16  Kl[2][64 * 64];   // swizzled linear [row][chunk^row&7]
  __shared__ __align__(16) short Vt[2][64][ALDP];  // V^T [d][key], padded
  __shared__ __align__(16) short Pl[128][ALDP];

  int t = threadIdx.x;
  int lane = t & 63, w = t >> 6;                   // w in 0..7
  int l15 = lane & 15, quad = lane >> 4;
  int bh = blockIdx.x;
  int qt = blockIdx.y;                             // 128-row q-tile
  int b = bh >> 4, hh = bh & 15;

  const bf16* q = qkv;
  const bf16* k = qkv + 1024;
  const bf16* v = qkv + 2048;

  // K staging via DMA: wave w stages rows w*8..w*8+7; chunk pre-swizzled so the
  // linear LDS write produces layout [row][ (c ^ (row&7))*8 ]; (row&7) == lane>>3.
  int kcol = ((lane & 7) ^ (lane >> 3)) * 8;
  const bf16* kg0 = k + (size_t)(b * MMK + w * 8 + (lane >> 3)) * QKVS + hh * DHEAD + kcol;

  // V staging source: 512 threads x 8 elems (one bf16x8 load, 8 scalar stores)
  int srow = t >> 3, sc0 = (t & 7) * 8;
  const bf16* vg = v + (size_t)(b * MMK + srow) * QKVS + hh * DHEAD + sc0;

  bf16x8 qfrag[2];
  {
    const bf16* qp = q + (size_t)(b * NN + qt * 128 + w * 16 + l15) * QKVS + hh * DHEAD + quad * 8;
    #pragma unroll
    for (int ks = 0; ks < 2; ++ks) {
      bf16x8 raw = *(const bf16x8*)(qp + ks * 32);
      bf16x8 sc;
      #pragma unroll
      for (int e = 0; e < 8; ++e) sc[e] = bfbits(bitsbf(raw[e]) * 0.03125f);
      qfrag[ks] = sc;
    }
  }

  // prologue: tile 0 -> buffer 0
  gload_lds16(kg0, &Kl[0][w * 512]);
  {
    bf16x8 v0 = *(const bf16x8*)vg;
    #pragma unroll
    for (int e = 0; e < 8; ++e) Vt[0][sc0 + e][srow] = v0[e];
  }

  f32x4 Oacc[4] = {{}, {}, {}, {}};
  float mrow[4] = {-1e30f, -1e30f, -1e30f, -1e30f};
  float lrow[4] = {0.f, 0.f, 0.f, 0.f};

  int cur = 0;
  for (int kt = 0; kt < MMK / 64; ++kt) {
    __syncthreads();             // buf[cur] valid (drains DMA vmcnt + prev V stores)
    int nxt = cur ^ 1;
    bool more = (kt + 1 < MMK / 64);
    bf16x8 nv0;
    if (more) {
      nv0 = *(const bf16x8*)(vg + (size_t)(kt + 1) * 64 * QKVS);   // issue V load first
      gload_lds16(kg0 + (size_t)(kt + 1) * 64 * QKVS, &Kl[nxt][w * 512]);
    }

    // QK^T from swizzled K: row = j*16+l15, chunk = (ks*4+quad) ^ (l15&7)
    f32x4 S[4] = {{}, {}, {}, {}};
    #pragma unroll
    for (int ks = 0; ks < 2; ++ks) {
      #pragma unroll
      for (int j = 0; j < 4; ++j) {
        bf16x8 bfr = *(const bf16x8*)&Kl[cur][(j * 16 + l15) * 64 + (((ks * 4 + quad) ^ (l15 & 7)) * 8)];
        S[j] = __builtin_amdgcn_mfma_f32_16x16x32_bf16(qfrag[ks], bfr, S[j], 0, 0, 0);
      }
    }

    #pragma unroll
    for (int r = 0; r < 4; ++r) {
      float tm = fmaxf(fmaxf(S[0][r], S[1][r]), fmaxf(S[2][r], S[3][r]));
      tm = fmaxf(tm, __shfl_xor(tm, 1, 64));
      tm = fmaxf(tm, __shfl_xor(tm, 2, 64));
      tm = fmaxf(tm, __shfl_xor(tm, 4, 64));
      tm = fmaxf(tm, __shfl_xor(tm, 8, 64));
      float mn = fmaxf(mrow[r], tm);
      float alpha = __expf(mrow[r] - mn);
      mrow[r] = mn;
      float rs = 0.f;
      #pragma unroll
      for (int j = 0; j < 4; ++j) {
        float p = __expf(S[j][r] - mn);
        S[j][r] = p;
        rs += p;
      }
      rs += __shfl_xor(rs, 1, 64);
      rs += __shfl_xor(rs, 2, 64);
      rs += __shfl_xor(rs, 4, 64);
      rs += __shfl_xor(rs, 8, 64);
      lrow[r] = lrow[r] * alpha + rs;
      #pragma unroll
      for (int j = 0; j < 4; ++j) {
        Oacc[j][r] *= alpha;
        Pl[w * 16 + quad * 4 + r][j * 16 + l15] = bfbits(S[j][r]);
      }
    }

    // PV from Vt[cur] and Pl (Pl band w*16.. is wave-private; DS in-order per wave)
    #pragma unroll
    for (int ks = 0; ks < 2; ++ks) {
      bf16x8 pa = *(const bf16x8*)&Pl[w * 16 + l15][ks * 32 + quad * 8];
      #pragma unroll
      for (int j = 0; j < 4; ++j) {
        bf16x8 vb = *(const bf16x8*)&Vt[cur][j * 16 + l15][ks * 32 + quad * 8];
        Oacc[j] = __builtin_amdgcn_mfma_f32_16x16x32_bf16(pa, vb, Oacc[j], 0, 0, 0);
      }
    }

    // write-late: stage next V tile into Vt[nxt]
    if (more) {
      #pragma unroll
      for (int e = 0; e < 8; ++e) Vt[nxt][sc0 + e][srow] = nv0[e];
    }
    cur = nxt;
  }

  #pragma unroll
  for (int r = 0; r < 4; ++r) {
    float inv = 1.0f / lrow[r];
    bf16* op = o + (size_t)(b * NN + qt * 128 + w * 16 + quad * 4 + r) * DIM + hh * DHEAD;
    #pragma unroll
    for (int j = 0; j < 4; ++j)
      op[j * 16 + l15] = __float2bfloat16(Oacc[j][r] * inv);
  }
}

// ---------------- host orchestration ----------------
extern "C" void kernel_launch(void* const* d_in, const int* in_sizes, int n_in,
                              void* d_out, int out_size, void* d_ws, size_t ws_size,
                              hipStream_t stream) {
  const float* x_in = (const float*)d_in[0];
  const float* m    = (const float*)d_in[1];
  const float* Wq   = (const float*)d_in[2];
  const float* Wk   = (const float*)d_in[3];
  const float* Wv   = (const float*)d_in[4];
  const float* Wo   = (const float*)d_in[5];
  const float* bo   = (const float*)d_in[6];
  const float* ln1w = (const float*)d_in[7];
  const float* ln1b = (const float*)d_in[8];
  const float* W1   = (const float*)d_in[9];
  const float* b1   = (const float*)d_in[10];
  const float* W2   = (const float*)d_in[11];
  const float* b2   = (const float*)d_in[12];
  const float* ln2w = (const float*)d_in[13];
  const float* ln2b = (const float*)d_in[14];

  float* xf = (float*)d_out;   // fp32 residual in d_out

  char* ws = (char*)d_ws;
  // layout (44 MB): h [0,8), mb [8,16), qkv [16,40) packed (4096 x 3072 bf16),
  //                 wt [40,44). ffh (4096x2048) reuses [16,32) in MLP phase.
  bf16* h    = (bf16*)(ws + 0);
  bf16* mb   = (bf16*)(ws + (8u  << 20));
  bf16* qkv  = (bf16*)(ws + (16u << 20));
  bf16* ffh  = (bf16*)(ws + (16u << 20));
  bf16* wt   = (bf16*)(ws + (40u << 20));

  const int NTOK = ROWS * DIM;

  hipMemcpyAsync(xf, x_in, (size_t)NTOK * sizeof(float), hipMemcpyDeviceToDevice, stream);
  f2b_kernel<<<dim3((NTOK + 255) / 256), dim3(256), 0, stream>>>(m, mb, NTOK);

  dim3 blk(256);
  dim3 ablk(512);
  dim3 tblk(32, 8);
  dim3 g_n1(DIM / 64, ROWS / BM);       // (16, 32) = 512 blocks, JT=2
  dim3 g_n2(2048 / 128, ROWS / BM);     // (16, 32) = 512 blocks, JT=4
  dim3 tr_1k(DIM / 32, DIM / 32);
  dim3 tr_w1(2048 / 32, DIM / 32);
  dim3 tr_w2(DIM / 32, 2048 / 32);
  dim3 attn_grid(BB * HEADS, NN / 128); // (64, 8) = 512 blocks, xcd = bh & 7

  for (int L = 0; L < DEPTH; ++L) {
    const float* WqL = Wq + (size_t)L * DIM * DIM;
    const float* WkL = Wk + (size_t)L * DIM * DIM;
    const float* WvL = Wv + (size_t)L * DIM * DIM;
    const float* WoL = Wo + (size_t)L * DIM * DIM;
    const float* W1L = W1 + (size_t)L * DIM * MLPD;
    const float* W2L = W2 + (size_t)L * MLPD * DIM;

    // --- cross-attention block ---
    ln_kernel<<<dim3(ROWS), blk, 0, stream>>>(xf, ln1w + L * DIM, ln1b + L * DIM, h);

    // K|V fused: Bt = [Wk^T ; Wv^T] (2048 x 1024) in wt
    transpose_f2b<<<tr_1k, tblk, 0, stream>>>(WkL, wt, DIM, 0, 0, DIM);
    transpose_f2b<<<tr_1k, tblk, 0, stream>>>(WvL, wt + 1024 * 1024, DIM, 0, 0, DIM);
    gemm_tile<4><<<g_n2, blk, 0, stream>>>(mb, wt, nullptr, qkv + 1024, nullptr, QKVS, DIM, MODE_PLAIN);

    transpose_f2b<<<tr_1k, tblk, 0, stream>>>(WqL, wt, DIM, 0, 0, DIM);
    gemm_tile<2><<<g_n1, blk, 0, stream>>>(h, wt, nullptr, qkv, nullptr, QKVS, DIM, MODE_PLAIN);

    attn_mfma_kernel<<<attn_grid, ablk, 0, stream>>>(qkv, h);

    transpose_f2b<<<tr_1k, tblk, 0, stream>>>(WoL, wt, DIM, 0, 0, DIM);
    gemm_tile<2><<<g_n1, blk, 0, stream>>>(h, wt, bo + L * DIM, nullptr, xf, DIM, DIM, MODE_RES);

    // --- MLP block (two N=2048 halves; ffh reuses qkv space) ---
    ln_kernel<<<dim3(ROWS), blk, 0, stream>>>(xf, ln2w + L * DIM, ln2b + L * DIM, h);

    for (int half = 0; half < 2; ++half) {
      transpose_f2b<<<tr_w1, tblk, 0, stream>>>(W1L, wt, MLPD, 0, half * 2048, DIM);
      gemm_tile<4><<<g_n2, blk, 0, stream>>>(h, wt, b1 + (size_t)L * MLPD + half * 2048, ffh, nullptr,
                                             2048, DIM, MODE_GELU);
      transpose_f2b<<<tr_w2, tblk, 0, stream>>>(W2L, wt, DIM, half * 2048, 0, 2048);
      gemm_tile<2><<<g_n1, blk, 0, stream>>>(ffh, wt, (half == 0) ? (b2 + (size_t)L * DIM) : nullptr,
                                             nullptr, xf, DIM, 2048, MODE_RES);
    }
  }
}

// Round 10
// 1503.103 us; speedup vs baseline: 1.2018x; 1.0081x over previous
//
#include <hip/hip_runtime.h>
#include <hip/hip_bf16.h>
#include <math.h>

typedef __hip_bfloat16 bf16;
typedef __attribute__((ext_vector_type(8))) short bf16x8;
typedef __attribute__((ext_vector_type(4))) float f32x4;

#define DEPTH  4
#define HEADS  16
#define DIM    1024
#define DHEAD  64
#define MLPD   4096
#define BB     4
#define NN     1024
#define MMK    1024
#define ROWS   (BB*NN)     // 4096 token rows
#define QKVS   3072        // packed qkv row stride

__device__ inline float bitsbf(short s) {
  union { float f; unsigned u; } c; c.u = ((unsigned)(unsigned short)s) << 16; return c.f;
}
__device__ inline short bfbits(float f) {
  bf16 h = __float2bfloat16(f); return *(short*)&h;
}

// async global->LDS 16B per lane. LDS dest = wave-uniform base + lane*16B.
__device__ inline void gload_lds16(const bf16* g, bf16* l) {
  __builtin_amdgcn_global_load_lds((const __attribute__((address_space(1))) unsigned int*)g,
                                   (__attribute__((address_space(3))) unsigned int*)l, 16, 0, 0);
}

// ---------------- f32 -> bf16 convert ----------------
__global__ __launch_bounds__(256) void f2b_kernel(const float* __restrict__ in, bf16* __restrict__ out, int n) {
  int i = blockIdx.x * 256 + threadIdx.x;
  if (i < n) out[i] = __float2bfloat16(in[i]);
}

// ---------------- generalized transpose + f32->bf16 ----------------
// out[n][k] = bf16( in[(rowOff + k) * inStride + colOff + n] )
__global__ __launch_bounds__(256) void transpose_f2b(const float* __restrict__ in, bf16* __restrict__ out,
                                                     int inStride, int rowOff, int colOff, int outStride) {
  __shared__ float tile[32][33];
  int n0 = blockIdx.x * 32, k0 = blockIdx.y * 32;
  int tx = threadIdx.x, ty = threadIdx.y;          // 32 x 8
  #pragma unroll
  for (int i = 0; i < 32; i += 8)
    tile[ty + i][tx] = in[(size_t)(rowOff + k0 + ty + i) * inStride + colOff + n0 + tx];
  __syncthreads();
  #pragma unroll
  for (int i = 0; i < 32; i += 8)
    out[(size_t)(n0 + ty + i) * outStride + k0 + tx] = __float2bfloat16(tile[tx][ty + i]);
}

// ---------------- layernorm: f32 in -> bf16 out ----------------
__global__ __launch_bounds__(256) void ln_kernel(const float* __restrict__ x, const float* __restrict__ w,
                                                 const float* __restrict__ b, bf16* __restrict__ out) {
  int row = blockIdx.x, t = threadIdx.x;
  const float* xr = x + (size_t)row * DIM;
  float4 xv = *(const float4*)(xr + t * 4);
  float s  = xv.x + xv.y + xv.z + xv.w;
  float s2 = xv.x * xv.x + xv.y * xv.y + xv.z * xv.z + xv.w * xv.w;
  #pragma unroll
  for (int off = 32; off; off >>= 1) { s += __shfl_xor(s, off, 64); s2 += __shfl_xor(s2, off, 64); }
  __shared__ float sh_s[4], sh_s2[4], sh_mu, sh_rstd;
  int wid = t >> 6;
  if ((t & 63) == 0) { sh_s[wid] = s; sh_s2[wid] = s2; }
  __syncthreads();
  if (t == 0) {
    float S1 = sh_s[0] + sh_s[1] + sh_s[2] + sh_s[3];
    float S2 = sh_s2[0] + sh_s2[1] + sh_s2[2] + sh_s2[3];
    float mu = S1 * (1.0f / DIM);
    float var = S2 * (1.0f / DIM) - mu * mu;
    sh_mu = mu; sh_rstd = rsqrtf(var + 1e-5f);
  }
  __syncthreads();
  float mu = sh_mu, rstd = sh_rstd;
  float4 wv = *(const float4*)(w + t * 4);
  float4 bv = *(const float4*)(b + t * 4);
  bf16* orow = out + (size_t)row * DIM + t * 4;
  orow[0] = __float2bfloat16((xv.x - mu) * rstd * wv.x + bv.x);
  orow[1] = __float2bfloat16((xv.y - mu) * rstd * wv.y + bv.y);
  orow[2] = __float2bfloat16((xv.z - mu) * rstd * wv.z + bv.z);
  orow[3] = __float2bfloat16((xv.w - mu) * rstd * wv.w + bv.w);
}

// ---------------- GEMM BM=128 x BN=(JT*32), BK=64 (round-6 inner loop) ------------
// NEW: col-major dispatch — blockIdx.x = ROW block, blockIdx.y = COL block.
// flat id = bx + gridX*by with gridX=32 -> XCD = bx%8 = rowblock%8: each XCD's
// 4 A-panels (1 MB) stay L2-resident across all col-blocks, cutting A re-fetch
// from L3 ~16x (XCD pinning proven on attn in round 4).
#define MODE_PLAIN 0
#define MODE_GELU  1
#define MODE_RES   2
#define BM 128
#define BK2 64

template<int JT>
__global__ __launch_bounds__(256) void gemm_tile(const bf16* __restrict__ A, const bf16* __restrict__ Bt,
                                                 const float* __restrict__ bias, bf16* __restrict__ outb,
                                                 float* __restrict__ resf, int outStride, int K, int mode) {
  constexpr int BN = JT * 32;
  __shared__ __align__(16) bf16 As[2][BM * BK2];   // 2 x 16 KB
  __shared__ __align__(16) bf16 Bs[2][BN * BK2];   // 2 x (16 or 8) KB
  int t = threadIdx.x;
  int w = t >> 6, l = t & 63;
  int l15 = l & 15, quad = l >> 4;
  int l8 = l & 7, lh = l >> 3;
  int row0 = blockIdx.x * BM, col0 = blockIdx.y * BN;   // swapped roles
  int wm = (w >> 1) * 64, wn = (w & 1) * (JT * 16);

  f32x4 acc[4][JT] = {};

  int swk = (l8 ^ lh) * 8;
  const bf16* agB = A  + (size_t)(row0 + w * 32 + lh) * K + swk;
  const bf16* bgB = Bt + (size_t)(col0 + (JT == 4 ? w * 32 : w * 16) + lh) * K + swk;

  // prologue: tile 0 -> buf 0
  #pragma unroll
  for (int i = 0; i < 4; ++i)
    gload_lds16(agB + (size_t)(i * 8) * K, &As[0][w * 2048 + i * 512]);
  #pragma unroll
  for (int i = 0; i < (JT == 4 ? 4 : 2); ++i)
    gload_lds16(bgB + (size_t)(i * 8) * K, &Bs[0][w * (JT == 4 ? 2048 : 1024) + i * 512]);

  int cur = 0;
  for (int k0 = 0; k0 < K; k0 += BK2) {
    __syncthreads();             // drains DMA (vmcnt) + prior ds reads: buf[cur] valid
    int nxt = cur ^ 1;
    if (k0 + BK2 < K) {          // prefetch next tile under this tile's compute
      #pragma unroll
      for (int i = 0; i < 4; ++i)
        gload_lds16(agB + (size_t)(i * 8) * K + k0 + BK2, &As[nxt][w * 2048 + i * 512]);
      #pragma unroll
      for (int i = 0; i < (JT == 4 ? 4 : 2); ++i)
        gload_lds16(bgB + (size_t)(i * 8) * K + k0 + BK2, &Bs[nxt][w * (JT == 4 ? 2048 : 1024) + i * 512]);
    }
    #pragma unroll
    for (int ks2 = 0; ks2 < 2; ++ks2) {
      bf16x8 af[4], bfr[JT];
      #pragma unroll
      for (int i = 0; i < 4; ++i) {
        int R = wm + i * 16 + l15;
        af[i] = *(const bf16x8*)&As[cur][R * 64 + (((quad + 4 * ks2) ^ (l15 & 7)) * 8)];
      }
      #pragma unroll
      for (int j = 0; j < JT; ++j) {
        int R = wn + j * 16 + l15;
        bfr[j] = *(const bf16x8*)&Bs[cur][R * 64 + (((quad + 4 * ks2) ^ (l15 & 7)) * 8)];
      }
      #pragma unroll
      for (int i = 0; i < 4; ++i)
        #pragma unroll
        for (int j = 0; j < JT; ++j)
          acc[i][j] = __builtin_amdgcn_mfma_f32_16x16x32_bf16(af[i], bfr[j], acc[i][j], 0, 0, 0);
    }
    cur = nxt;
  }

  // epilogue: row = row0+wm+i*16+quad*4+r, col = col0+wn+j*16+l15
  #pragma unroll
  for (int i = 0; i < 4; ++i) {
    #pragma unroll
    for (int j = 0; j < JT; ++j) {
      int gcol = col0 + wn + j * 16 + l15;
      float bval = (mode != MODE_PLAIN && bias != nullptr) ? bias[gcol] : 0.0f;
      #pragma unroll
      for (int r = 0; r < 4; ++r) {
        int grow = row0 + wm + i * 16 + quad * 4 + r;
        float val = acc[i][j][r];
        size_t idx = (size_t)grow * outStride + gcol;
        if (mode == MODE_RES) {
          resf[idx] = resf[idx] + val + bval;
        } else {
          if (mode == MODE_GELU) {
            float u = val + bval;
            val = 0.5f * u * (1.0f + erff(u * 0.70710678118654752f));
          }
          outb[idx] = __float2bfloat16(val);
        }
      }
    }
  }
}

// ---------------- MFMA flash attention v2-wide: QBLK=128, 8 waves --------------------
// Round-9 structure + V-store swizzle: V^T element [d][key] stored at column
// key ^ ((d>>3 & 7)*8), row stride 64. Write banks = 4*(w^(t&7)) + s/2 -> all 32
// banks, conflict-free (was 16-way). Reads use inverse XOR on chunk index and sit
// at the b128 bandwidth minimum.
#define ALDP 72

__global__ __launch_bounds__(512) void attn_mfma_kernel(const bf16* __restrict__ qkv, bf16* __restrict__ o) {
  __shared__ __align__(16) bf16  Kl[2][64 * 64];   // swizzled linear [row][chunk^row&7]
  __shared__ __align__(16) short Vt[2][64][64];    // V^T [d][key ^ ((d>>3&7)*8)]
  __shared__ __align__(16) short Pl[128][ALDP];

  int t = threadIdx.x;
  int lane = t & 63, w = t >> 6;                   // w in 0..7
  int l15 = lane & 15, quad = lane >> 4;
  int bh = blockIdx.x;
  int qt = blockIdx.y;                             // 128-row q-tile
  int b = bh >> 4, hh = bh & 15;

  const bf16* q = qkv;
  const bf16* k = qkv + 1024;
  const bf16* v = qkv + 2048;

  // K staging via DMA: wave w stages rows w*8..w*8+7; chunk pre-swizzled so the
  // linear LDS write produces layout [row][ (c ^ (row&7))*8 ]; (row&7) == lane>>3.
  int kcol = ((lane & 7) ^ (lane >> 3)) * 8;
  const bf16* kg0 = k + (size_t)(b * MMK + w * 8 + (lane >> 3)) * QKVS + hh * DHEAD + kcol;

  // V staging source: 512 threads x 8 elems; store col swizzled by (d>>3)&7 = t&7
  int srow = t >> 3, sc0 = (t & 7) * 8;
  int vcol = srow ^ ((t & 7) << 3);                // key-slot after swizzle
  const bf16* vg = v + (size_t)(b * MMK + srow) * QKVS + hh * DHEAD + sc0;

  bf16x8 qfrag[2];
  {
    const bf16* qp = q + (size_t)(b * NN + qt * 128 + w * 16 + l15) * QKVS + hh * DHEAD + quad * 8;
    #pragma unroll
    for (int ks = 0; ks < 2; ++ks) {
      bf16x8 raw = *(const bf16x8*)(qp + ks * 32);
      bf16x8 sc;
      #pragma unroll
      for (int e = 0; e < 8; ++e) sc[e] = bfbits(bitsbf(raw[e]) * 0.03125f);
      qfrag[ks] = sc;
    }
  }

  // prologue: tile 0 -> buffer 0
  gload_lds16(kg0, &Kl[0][w * 512]);
  {
    bf16x8 v0 = *(const bf16x8*)vg;
    #pragma unroll
    for (int e = 0; e < 8; ++e) Vt[0][sc0 + e][vcol] = v0[e];
  }

  f32x4 Oacc[4] = {{}, {}, {}, {}};
  float mrow[4] = {-1e30f, -1e30f, -1e30f, -1e30f};
  float lrow[4] = {0.f, 0.f, 0.f, 0.f};

  int cur = 0;
  for (int kt = 0; kt < MMK / 64; ++kt) {
    __syncthreads();             // buf[cur] valid (drains DMA vmcnt + prev V stores)
    int nxt = cur ^ 1;
    bool more = (kt + 1 < MMK / 64);
    bf16x8 nv0;
    if (more) {
      nv0 = *(const bf16x8*)(vg + (size_t)(kt + 1) * 64 * QKVS);   // issue V load first
      gload_lds16(kg0 + (size_t)(kt + 1) * 64 * QKVS, &Kl[nxt][w * 512]);
    }

    // QK^T from swizzled K: row = j*16+l15, chunk = (ks*4+quad) ^ (l15&7)
    f32x4 S[4] = {{}, {}, {}, {}};
    #pragma unroll
    for (int ks = 0; ks < 2; ++ks) {
      #pragma unroll
      for (int j = 0; j < 4; ++j) {
        bf16x8 bfr = *(const bf16x8*)&Kl[cur][(j * 16 + l15) * 64 + (((ks * 4 + quad) ^ (l15 & 7)) * 8)];
        S[j] = __builtin_amdgcn_mfma_f32_16x16x32_bf16(qfrag[ks], bfr, S[j], 0, 0, 0);
      }
    }

    #pragma unroll
    for (int r = 0; r < 4; ++r) {
      float tm = fmaxf(fmaxf(S[0][r], S[1][r]), fmaxf(S[2][r], S[3][r]));
      tm = fmaxf(tm, __shfl_xor(tm, 1, 64));
      tm = fmaxf(tm, __shfl_xor(tm, 2, 64));
      tm = fmaxf(tm, __shfl_xor(tm, 4, 64));
      tm = fmaxf(tm, __shfl_xor(tm, 8, 64));
      float mn = fmaxf(mrow[r], tm);
      float alpha = __expf(mrow[r] - mn);
      mrow[r] = mn;
      float rs = 0.f;
      #pragma unroll
      for (int j = 0; j < 4; ++j) {
        float p = __expf(S[j][r] - mn);
        S[j][r] = p;
        rs += p;
      }
      rs += __shfl_xor(rs, 1, 64);
      rs += __shfl_xor(rs, 2, 64);
      rs += __shfl_xor(rs, 4, 64);
      rs += __shfl_xor(rs, 8, 64);
      lrow[r] = lrow[r] * alpha + rs;
      #pragma unroll
      for (int j = 0; j < 4; ++j) {
        Oacc[j][r] *= alpha;
        Pl[w * 16 + quad * 4 + r][j * 16 + l15] = bfbits(S[j][r]);
      }
    }

    // PV from Vt[cur] (inverse-swizzled chunk) and Pl (wave-private band)
    #pragma unroll
    for (int ks = 0; ks < 2; ++ks) {
      bf16x8 pa = *(const bf16x8*)&Pl[w * 16 + l15][ks * 32 + quad * 8];
      #pragma unroll
      for (int j = 0; j < 4; ++j) {
        int d = j * 16 + l15;
        int xr = (2 * j + (l15 >> 3)) & 7;
        bf16x8 vb = *(const bf16x8*)&Vt[cur][d][(((ks * 4 + quad) ^ xr) * 8)];
        Oacc[j] = __builtin_amdgcn_mfma_f32_16x16x32_bf16(pa, vb, Oacc[j], 0, 0, 0);
      }
    }

    // write-late: stage next V tile into Vt[nxt]
    if (more) {
      #pragma unroll
      for (int e = 0; e < 8; ++e) Vt[nxt][sc0 + e][vcol] = nv0[e];
    }
    cur = nxt;
  }

  #pragma unroll
  for (int r = 0; r < 4; ++r) {
    float inv = 1.0f / lrow[r];
    bf16* op = o + (size_t)(b * NN + qt * 128 + w * 16 + quad * 4 + r) * DIM + hh * DHEAD;
    #pragma unroll
    for (int j = 0; j < 4; ++j)
      op[j * 16 + l15] = __float2bfloat16(Oacc[j][r] * inv);
  }
}

// ---------------- host orchestration ----------------
extern "C" void kernel_launch(void* const* d_in, const int* in_sizes, int n_in,
                              void* d_out, int out_size, void* d_ws, size_t ws_size,
                              hipStream_t stream) {
  const float* x_in = (const float*)d_in[0];
  const float* m    = (const float*)d_in[1];
  const float* Wq   = (const float*)d_in[2];
  const float* Wk   = (const float*)d_in[3];
  const float* Wv   = (const float*)d_in[4];
  const float* Wo   = (const float*)d_in[5];
  const float* bo   = (const float*)d_in[6];
  const float* ln1w = (const float*)d_in[7];
  const float* ln1b = (const float*)d_in[8];
  const float* W1   = (const float*)d_in[9];
  const float* b1   = (const float*)d_in[10];
  const float* W2   = (const float*)d_in[11];
  const float* b2   = (const float*)d_in[12];
  const float* ln2w = (const float*)d_in[13];
  const float* ln2b = (const float*)d_in[14];

  float* xf = (float*)d_out;   // fp32 residual in d_out

  char* ws = (char*)d_ws;
  // layout (44 MB): h [0,8), mb [8,16), qkv [16,40) packed (4096 x 3072 bf16),
  //                 wt [40,44). ffh (4096x2048) reuses [16,32) in MLP phase.
  bf16* h    = (bf16*)(ws + 0);
  bf16* mb   = (bf16*)(ws + (8u  << 20));
  bf16* qkv  = (bf16*)(ws + (16u << 20));
  bf16* ffh  = (bf16*)(ws + (16u << 20));
  bf16* wt   = (bf16*)(ws + (40u << 20));

  const int NTOK = ROWS * DIM;

  hipMemcpyAsync(xf, x_in, (size_t)NTOK * sizeof(float), hipMemcpyDeviceToDevice, stream);
  f2b_kernel<<<dim3((NTOK + 255) / 256), dim3(256), 0, stream>>>(m, mb, NTOK);

  dim3 blk(256);
  dim3 ablk(512);
  dim3 tblk(32, 8);
  dim3 g_n1(ROWS / BM, DIM / 64);       // (32, 16): bx=rowblk -> XCD = rowblk%8
  dim3 g_n2(ROWS / BM, 2048 / 128);     // (32, 16)
  dim3 tr_1k(DIM / 32, DIM / 32);
  dim3 tr_w1(2048 / 32, DIM / 32);
  dim3 tr_w2(DIM / 32, 2048 / 32);
  dim3 attn_grid(BB * HEADS, NN / 128); // (64, 8) = 512 blocks, xcd = bh & 7

  for (int L = 0; L < DEPTH; ++L) {
    const float* WqL = Wq + (size_t)L * DIM * DIM;
    const float* WkL = Wk + (size_t)L * DIM * DIM;
    const float* WvL = Wv + (size_t)L * DIM * DIM;
    const float* WoL = Wo + (size_t)L * DIM * DIM;
    const float* W1L = W1 + (size_t)L * DIM * MLPD;
    const float* W2L = W2 + (size_t)L * MLPD * DIM;

    // --- cross-attention block ---
    ln_kernel<<<dim3(ROWS), blk, 0, stream>>>(xf, ln1w + L * DIM, ln1b + L * DIM, h);

    // K|V fused: Bt = [Wk^T ; Wv^T] (2048 x 1024) in wt
    transpose_f2b<<<tr_1k, tblk, 0, stream>>>(WkL, wt, DIM, 0, 0, DIM);
    transpose_f2b<<<tr_1k, tblk, 0, stream>>>(WvL, wt + 1024 * 1024, DIM, 0, 0, DIM);
    gemm_tile<4><<<g_n2, blk, 0, stream>>>(mb, wt, nullptr, qkv + 1024, nullptr, QKVS, DIM, MODE_PLAIN);

    transpose_f2b<<<tr_1k, tblk, 0, stream>>>(WqL, wt, DIM, 0, 0, DIM);
    gemm_tile<2><<<g_n1, blk, 0, stream>>>(h, wt, nullptr, qkv, nullptr, QKVS, DIM, MODE_PLAIN);

    attn_mfma_kernel<<<attn_grid, ablk, 0, stream>>>(qkv, h);

    transpose_f2b<<<tr_1k, tblk, 0, stream>>>(WoL, wt, DIM, 0, 0, DIM);
    gemm_tile<2><<<g_n1, blk, 0, stream>>>(h, wt, bo + L * DIM, nullptr, xf, DIM, DIM, MODE_RES);

    // --- MLP block (two N=2048 halves; ffh reuses qkv space) ---
    ln_kernel<<<dim3(ROWS), blk, 0, stream>>>(xf, ln2w + L * DIM, ln2b + L * DIM, h);

    for (int half = 0; half < 2; ++half) {
      transpose_f2b<<<tr_w1, tblk, 0, stream>>>(W1L, wt, MLPD, 0, half * 2048, DIM);
      gemm_tile<4><<<g_n2, blk, 0, stream>>>(h, wt, b1 + (size_t)L * MLPD + half * 2048, ffh, nullptr,
                                             2048, DIM, MODE_GELU);
      transpose_f2b<<<tr_w2, tblk, 0, stream>>>(W2L, wt, DIM, half * 2048, 0, 2048);
      gemm_tile<2><<<g_n1, blk, 0, stream>>>(ffh, wt, (half == 0) ? (b2 + (size_t)L * DIM) : nullptr,
                                             nullptr, xf, DIM, 2048, MODE_RES);
    }
  }
}